// Round 3
// baseline (735.241 us; speedup 1.0000x reference)
//
#include <hip/hip_runtime.h>

// GCN: N=100000 nodes (4 feats), E=3.2M edges, G=1024 graphs.
// out = mean-pool(tanh(gcn2(tanh(gcn1(embed(x)))))) @ W3.T + b3
//
// gcn_conv rewritten: u[i] = (h[i] @ W^T) * dinv[i];
// out[c] = dinv[c] * (sum_{edges r->c} u[r] + u[c]) + b   (self-loop folded in)
//
// R3: global atomics are capped at ~19.4G transactions/s on MI355X (k_deg ==
// k_scatter16 == 165us for 3.2M line-transactions each). So: bucket edges by
// dst (128 dst nodes/bucket, exact two-pass placement with per-block LDS
// pre-aggregation -> only ~200K global atomics), then aggregate per bucket in
// LDS (LDS atomics are ~32/cyc/CU). Degree = bucket run counts (free).
// Layer epilogues (tanh + next W) fused into the aggregation kernels.

constexpr int BLK = 256;
constexpr int NPB = 128;            // dst nodes per bucket
constexpr int MAXB = 784;           // >= ceil(100000/128)=782, padded

__global__ void k_zero(int* __restrict__ bucketCnt) {
    int t = threadIdx.x;
    if (t < MAXB) bucketCnt[t] = 0;
}

// Count edges per bucket (per-block LDS histogram, one global add per block/bucket)
__global__ void k_count(const int* __restrict__ col, int* __restrict__ bucketCnt,
                        int E, int B) {
    __shared__ int lcnt[MAXB];
    int chunk = (E + gridDim.x - 1) / gridDim.x;
    int begin = blockIdx.x * chunk;
    int end = min(E, begin + chunk);
    for (int t = threadIdx.x; t < MAXB; t += BLK) lcnt[t] = 0;
    __syncthreads();
    for (int e = begin + threadIdx.x; e < end; e += BLK)
        atomicAdd(&lcnt[col[e] >> 7], 1);
    __syncthreads();
    for (int t = threadIdx.x; t < B; t += BLK) {
        int c = lcnt[t];
        if (c) atomicAdd(&bucketCnt[t], c);
    }
}

// Exclusive scan of bucketCnt -> starts[0..B], bucketPos[b]=starts[b]. 1 block, 1024 thr.
__global__ void k_scan(const int* __restrict__ bucketCnt, int* __restrict__ starts,
                       int* __restrict__ bucketPos, int B) {
    __shared__ int a[1024], bb[1024];
    int t = threadIdx.x;
    int v = (t < B) ? bucketCnt[t] : 0;
    a[t] = v;
    __syncthreads();
    int* src = a; int* dst = bb;
#pragma unroll
    for (int off = 1; off < 1024; off <<= 1) {
        dst[t] = src[t] + (t >= off ? src[t - off] : 0);
        __syncthreads();
        int* tmp = src; src = dst; dst = tmp;
    }
    if (t == 0) starts[0] = 0;
    if (t < B) {
        starts[t + 1] = src[t];           // inclusive
        bucketPos[t] = src[t] - v;        // exclusive
    }
}

// Place edges into buckets: entry = (dst_local<<17) | row  (row<2^17, dloc<128)
__global__ void k_place(const int* __restrict__ row, const int* __restrict__ col,
                        int* __restrict__ bucketPos, unsigned int* __restrict__ data,
                        int E, int B) {
    __shared__ int lcnt[MAXB];
    __shared__ int lbase[MAXB];
    int chunk = (E + gridDim.x - 1) / gridDim.x;
    int begin = blockIdx.x * chunk;
    int end = min(E, begin + chunk);
    for (int t = threadIdx.x; t < MAXB; t += BLK) lcnt[t] = 0;
    __syncthreads();
    for (int e = begin + threadIdx.x; e < end; e += BLK)
        atomicAdd(&lcnt[col[e] >> 7], 1);
    __syncthreads();
    for (int t = threadIdx.x; t < B; t += BLK) {
        int c = lcnt[t];
        lbase[t] = c ? atomicAdd(&bucketPos[t], c) : 0;
        lcnt[t] = 0;
    }
    __syncthreads();
    for (int e = begin + threadIdx.x; e < end; e += BLK) {
        int c = col[e];
        int b = c >> 7;
        int off = atomicAdd(&lcnt[b], 1);
        data[lbase[b] + off] = ((unsigned int)(c & 127) << 17) | (unsigned int)row[e];
    }
}

// Degree from bucket run counts; dinv = rsqrt(deg+1)  (self-loop)
__global__ void k_deg_dinv(const unsigned int* __restrict__ data,
                           const int* __restrict__ starts,
                           float* __restrict__ dinv, int n) {
    __shared__ float cnt[NPB];
    int b = blockIdx.x;
    if (threadIdx.x < NPB) cnt[threadIdx.x] = 0.0f;
    __syncthreads();
    int s = starts[b], e = starts[b + 1];
    for (int i = s + threadIdx.x; i < e; i += BLK)
        atomicAdd(&cnt[data[i] >> 17], 1.0f);
    __syncthreads();
    if (threadIdx.x < NPB) {
        int node = b * NPB + threadIdx.x;
        if (node < n) dinv[node] = rsqrtf(cnt[threadIdx.x] + 1.0f);
    }
}

// h0 = [x0*Wemb + bemb (4), x1, x2, x3]; u1 = (h0 @ W1^T) * dinv
__global__ void k_node1(const float4* __restrict__ x, const float* __restrict__ dinv,
                        const float* __restrict__ Wemb, const float* __restrict__ bemb,
                        const float* __restrict__ W1, float4* __restrict__ u1, int n) {
    int i = blockIdx.x * BLK + threadIdx.x;
    if (i >= n) return;
    float4 xi = x[i];
    float h0[7];
#pragma unroll
    for (int j = 0; j < 4; j++) h0[j] = xi.x * Wemb[j] + bemb[j];
    h0[4] = xi.y; h0[5] = xi.z; h0[6] = xi.w;
    float d = dinv[i];
    float s[16];
#pragma unroll
    for (int f = 0; f < 16; f++) {
        float t = 0.0f;
#pragma unroll
        for (int j = 0; j < 7; j++) t += h0[j] * W1[f * 7 + j];
        s[f] = t * d;
    }
#pragma unroll
    for (int q = 0; q < 4; q++)
        u1[i * 4 + q] = make_float4(s[q*4], s[q*4+1], s[q*4+2], s[q*4+3]);
}

// Layer-1 aggregation + fused epilogue: per bucket, LDS acc[128][16];
// h1 = tanh(dinv*(acc + u1_self) + b1); u2 = (h1 @ W2^T) * dinv
__global__ void k_agg1(const unsigned int* __restrict__ data, const int* __restrict__ starts,
                       const float* __restrict__ u1, const float* __restrict__ dinv,
                       const float* __restrict__ b1, const float* __restrict__ W2,
                       float* __restrict__ u2, int n) {
    __shared__ float acc[NPB * 16];
    int b = blockIdx.x;
    for (int t = threadIdx.x; t < NPB * 16; t += BLK) acc[t] = 0.0f;
    __syncthreads();
    int s = starts[b], cnt = starts[b + 1] - s;
    int f = threadIdx.x & 15;
    int esub = threadIdx.x >> 4;          // 16 edges per iteration
    for (int base = 0; base < cnt; base += 16) {
        int idx = base + esub;
        if (idx < cnt) {
            unsigned int p = data[s + idx];
            int r = (int)(p & 0x1FFFF);
            int dloc = (int)(p >> 17);
            atomicAdd(&acc[dloc * 16 + f], u1[r * 16 + f]);
        }
    }
    __syncthreads();
    if (threadIdx.x < NPB) {
        int node = b * NPB + threadIdx.x;
        if (node < n) {
            float d = dinv[node];
            float h[16];
#pragma unroll
            for (int j = 0; j < 16; j++)
                h[j] = tanhf(d * (acc[threadIdx.x * 16 + j] + u1[node * 16 + j]) + b1[j]);
#pragma unroll
            for (int g = 0; g < 8; g++) {
                float t = 0.0f;
#pragma unroll
                for (int j = 0; j < 16; j++) t += h[j] * W2[g * 16 + j];
                u2[node * 8 + g] = t * d;
            }
        }
    }
}

// Layer-2 aggregation + fused epilogue: h2 = tanh(dinv*(acc + u2_self) + b2)
__global__ void k_agg2(const unsigned int* __restrict__ data, const int* __restrict__ starts,
                       const float* __restrict__ u2, const float* __restrict__ dinv,
                       const float* __restrict__ b2, float* __restrict__ h2, int n) {
    __shared__ float acc[NPB * 8];
    int b = blockIdx.x;
    for (int t = threadIdx.x; t < NPB * 8; t += BLK) acc[t] = 0.0f;
    __syncthreads();
    int s = starts[b], cnt = starts[b + 1] - s;
    int f = threadIdx.x & 7;
    int esub = threadIdx.x >> 3;          // 32 edges per iteration
    for (int base = 0; base < cnt; base += 32) {
        int idx = base + esub;
        if (idx < cnt) {
            unsigned int p = data[s + idx];
            int r = (int)(p & 0x1FFFF);
            int dloc = (int)(p >> 17);
            atomicAdd(&acc[dloc * 8 + f], u2[r * 8 + f]);
        }
    }
    __syncthreads();
    if (threadIdx.x < NPB) {
        int node = b * NPB + threadIdx.x;
        if (node < n) {
            float d = dinv[node];
#pragma unroll
            for (int j = 0; j < 8; j++)
                h2[node * 8 + j] = tanhf(d * (acc[threadIdx.x * 8 + j] + u2[node * 8 + j]) + b2[j]);
        }
    }
}

// One wave per graph. batch is SORTED -> binary search node range, mean, dot W3.
__global__ void k_pool_out(const float4* __restrict__ h2q, const int* __restrict__ batch,
                           const float* __restrict__ W3, const float* __restrict__ b3,
                           float* __restrict__ out, int n) {
    int g = blockIdx.x;
    int lane = threadIdx.x;           // 64 threads = 1 wave
    int lo = 0, hi = n;
    while (lo < hi) { int m = (lo + hi) >> 1; if (batch[m] < g) lo = m + 1; else hi = m; }
    int start = lo;
    hi = n;
    while (lo < hi) { int m = (lo + hi) >> 1; if (batch[m] < g + 1) lo = m + 1; else hi = m; }
    int end = lo;

    float s[8];
#pragma unroll
    for (int f = 0; f < 8; f++) s[f] = 0.0f;
    for (int i = start + lane; i < end; i += 64) {
        float4 a0 = h2q[i * 2];
        float4 a1 = h2q[i * 2 + 1];
        s[0] += a0.x; s[1] += a0.y; s[2] += a0.z; s[3] += a0.w;
        s[4] += a1.x; s[5] += a1.y; s[6] += a1.z; s[7] += a1.w;
    }
#pragma unroll
    for (int off = 32; off >= 1; off >>= 1) {
#pragma unroll
        for (int f = 0; f < 8; f++) s[f] += __shfl_down(s[f], off, 64);
    }
    if (lane == 0) {
        float c = fmaxf((float)(end - start), 1.0f);
        float t = 0.0f;
#pragma unroll
        for (int f = 0; f < 8; f++) t += (s[f] / c) * W3[f];
        out[g] = t + b3[0];
    }
}

extern "C" void kernel_launch(void* const* d_in, const int* in_sizes, int n_in,
                              void* d_out, int out_size, void* d_ws, size_t ws_size,
                              hipStream_t stream) {
    const float* x    = (const float*)d_in[0];
    const int*   ei   = (const int*)d_in[1];
    const int*   batch= (const int*)d_in[2];
    const float* Wemb = (const float*)d_in[3];
    const float* bemb = (const float*)d_in[4];
    const float* W1   = (const float*)d_in[5];
    const float* b1   = (const float*)d_in[6];
    const float* W2   = (const float*)d_in[7];
    const float* b2   = (const float*)d_in[8];
    const float* W3   = (const float*)d_in[9];
    const float* b3   = (const float*)d_in[10];
    float* out = (float*)d_out;

    const int n = in_sizes[2];        // 100000
    const int E = in_sizes[1] / 2;    // 3200000
    const int G = out_size;           // 1024
    const int* row = ei;
    const int* col = ei + E;
    const int B = (n + NPB - 1) / NPB;   // 782

    // workspace (floats): dinv[n] | u1[16n] (h2 aliases first 8n) | u2[8n] |
    //                     bucketCnt[MAXB] | starts[MAXB+1] | bucketPos[MAXB] | data[E]
    float* ws   = (float*)d_ws;
    float* dinv = ws;                  // n
    float* u1   = ws + n;              // 16n
    float* u2   = ws + 17 * n;         // 8n
    float* h2   = u1;                  // aliases u1 (dead after k_agg1)
    int* bucketCnt = (int*)(ws + 25 * n);
    int* starts    = bucketCnt + MAXB;
    int* bucketPos = starts + MAXB + 1;
    unsigned int* data = (unsigned int*)(bucketPos + MAXB);  // E entries

    int gridN = (n + BLK - 1) / BLK;

    k_zero<<<1, 1024, 0, stream>>>(bucketCnt);
    k_count<<<128, BLK, 0, stream>>>(col, bucketCnt, E, B);
    k_scan<<<1, 1024, 0, stream>>>(bucketCnt, starts, bucketPos, B);
    k_place<<<256, BLK, 0, stream>>>(row, col, bucketPos, data, E, B);
    k_deg_dinv<<<B, BLK, 0, stream>>>(data, starts, dinv, n);
    k_node1<<<gridN, BLK, 0, stream>>>((const float4*)x, dinv, Wemb, bemb, W1,
                                       (float4*)u1, n);
    k_agg1<<<B, BLK, 0, stream>>>(data, starts, u1, dinv, b1, W2, u2, n);
    k_agg2<<<B, BLK, 0, stream>>>(data, starts, u2, dinv, b2, h2, n);
    k_pool_out<<<G, 64, 0, stream>>>((const float4*)h2, batch, W3, b3, out, n);
}

// Round 4
// 339.187 us; speedup vs baseline: 2.1677x; 2.1677x over previous
//
#include <hip/hip_runtime.h>

// GCN: N=100000 nodes (4 feats), E=3.2M edges, G=1024 graphs.
// out = mean-pool(tanh(gcn2(tanh(gcn1(embed(x)))))) @ W3.T + b3
//
// gcn_conv rewritten: u[i] = (h[i] @ W^T) * dinv[i];
// out[c] = dinv[c] * (sum_{edges r->c} u[r] + u[c]) + b   (self-loop folded in)
//
// R4: R3's LDS-atomic aggregation was latency-bound (4 edges/wave-iter,
// dependent load->atomic chain, 348us). Fix: full counting sort to CSR
// (bucket by dst>>7, then per-bucket LDS sort -> dst-sorted src list +
// row_ptr + dinv), then aggregate with one 16-thread group per dst node,
// register accumulation, zero atomics in the hot loops.

constexpr int BLK = 256;
constexpr int NPB = 128;            // dst nodes per bucket
constexpr int MAXB = 784;           // >= ceil(100000/128)=782
constexpr int CAP = 6144;           // LDS stage cap; bucket size ~Poisson(4092), +32 sigma

__global__ void k_init(int* __restrict__ bucketCnt, int* __restrict__ row_ptr,
                       int n, int E) {
    int t = threadIdx.x;
    if (t < MAXB) bucketCnt[t] = 0;
    if (t == 0) row_ptr[n] = E;
}

// Count edges per bucket (per-block LDS histogram, one global add per block/bucket)
__global__ void k_count(const int* __restrict__ col, int* __restrict__ bucketCnt,
                        int E, int B) {
    __shared__ int lcnt[MAXB];
    int chunk = (E + gridDim.x - 1) / gridDim.x;
    int begin = blockIdx.x * chunk;
    int end = min(E, begin + chunk);
    for (int t = threadIdx.x; t < MAXB; t += BLK) lcnt[t] = 0;
    __syncthreads();
    for (int e = begin + threadIdx.x; e < end; e += BLK)
        atomicAdd(&lcnt[col[e] >> 7], 1);
    __syncthreads();
    for (int t = threadIdx.x; t < B; t += BLK) {
        int c = lcnt[t];
        if (c) atomicAdd(&bucketCnt[t], c);
    }
}

// Exclusive scan of bucketCnt -> starts[0..B], bucketPos[b]=starts[b]. 1 block, 1024 thr.
__global__ void k_scan(const int* __restrict__ bucketCnt, int* __restrict__ starts,
                       int* __restrict__ bucketPos, int B) {
    __shared__ int a[1024], bb[1024];
    int t = threadIdx.x;
    int v = (t < B) ? bucketCnt[t] : 0;
    a[t] = v;
    __syncthreads();
    int* src = a; int* dst = bb;
#pragma unroll
    for (int off = 1; off < 1024; off <<= 1) {
        dst[t] = src[t] + (t >= off ? src[t - off] : 0);
        __syncthreads();
        int* tmp = src; src = dst; dst = tmp;
    }
    if (t == 0) starts[0] = 0;
    if (t < B) {
        starts[t + 1] = src[t];           // inclusive
        bucketPos[t] = src[t] - v;        // exclusive
    }
}

// Place edges into buckets: entry = (dst_local<<17) | src  (src<2^17, dloc<128)
__global__ void k_place(const int* __restrict__ row, const int* __restrict__ col,
                        int* __restrict__ bucketPos, unsigned int* __restrict__ data,
                        int E, int B) {
    __shared__ int lcnt[MAXB];
    __shared__ int lbase[MAXB];
    int chunk = (E + gridDim.x - 1) / gridDim.x;
    int begin = blockIdx.x * chunk;
    int end = min(E, begin + chunk);
    for (int t = threadIdx.x; t < MAXB; t += BLK) lcnt[t] = 0;
    __syncthreads();
    for (int e = begin + threadIdx.x; e < end; e += BLK)
        atomicAdd(&lcnt[col[e] >> 7], 1);
    __syncthreads();
    for (int t = threadIdx.x; t < B; t += BLK) {
        int c = lcnt[t];
        lbase[t] = c ? atomicAdd(&bucketPos[t], c) : 0;
        lcnt[t] = 0;
    }
    __syncthreads();
    for (int e = begin + threadIdx.x; e < end; e += BLK) {
        int c = col[e];
        int b = c >> 7;
        int off = atomicAdd(&lcnt[b], 1);
        data[lbase[b] + off] = ((unsigned int)(c & 127) << 17) | (unsigned int)row[e];
    }
}

// Per-bucket LDS counting sort (in place in data) + row_ptr + dinv.
__global__ void k_sort(unsigned int* __restrict__ data, const int* __restrict__ starts,
                       int* __restrict__ row_ptr, float* __restrict__ dinv, int n) {
    __shared__ unsigned int stage[CAP];
    __shared__ int hist[NPB];
    __shared__ int scanbuf[NPB];
    __shared__ int pos[NPB];
    int b = blockIdx.x;
    int t = threadIdx.x;
    int s = starts[b];
    int cnt = starts[b + 1] - s;
    for (int i = t; i < NPB; i += BLK) hist[i] = 0;
    __syncthreads();
    for (int i = t; i < cnt; i += BLK) {
        unsigned int p = data[s + i];
        if (i < CAP) stage[i] = p;
        atomicAdd(&hist[p >> 17], 1);
    }
    __syncthreads();
    int v = (t < NPB) ? hist[t] : 0;
    if (t < NPB) scanbuf[t] = v;
    __syncthreads();
#pragma unroll
    for (int off = 1; off < NPB; off <<= 1) {
        int add = 0;
        if (t < NPB && t >= off) add = scanbuf[t - off];
        __syncthreads();
        if (t < NPB) scanbuf[t] += add;
        __syncthreads();
    }
    if (t < NPB) {
        int excl = scanbuf[t] - v;        // within-bucket start of this dst
        pos[t] = excl;
        int node = b * NPB + t;
        if (node < n) {
            row_ptr[node] = s + excl;
            dinv[node] = rsqrtf((float)v + 1.0f);   // +1 self-loop
        }
    }
    __syncthreads();
    for (int i = t; i < cnt; i += BLK) {
        unsigned int p = (i < CAP) ? stage[i] : data[s + i];  // cnt>CAP is ~impossible
        int off = atomicAdd(&pos[p >> 17], 1);
        data[s + off] = p;
    }
}

// h0 = [x0*Wemb + bemb (4), x1, x2, x3]; u1 = (h0 @ W1^T) * dinv
__global__ void k_node1(const float4* __restrict__ x, const float* __restrict__ dinv,
                        const float* __restrict__ Wemb, const float* __restrict__ bemb,
                        const float* __restrict__ W1, float4* __restrict__ u1, int n) {
    int i = blockIdx.x * BLK + threadIdx.x;
    if (i >= n) return;
    float4 xi = x[i];
    float h0[7];
#pragma unroll
    for (int j = 0; j < 4; j++) h0[j] = xi.x * Wemb[j] + bemb[j];
    h0[4] = xi.y; h0[5] = xi.z; h0[6] = xi.w;
    float d = dinv[i];
    float s[16];
#pragma unroll
    for (int f = 0; f < 16; f++) {
        float t = 0.0f;
#pragma unroll
        for (int j = 0; j < 7; j++) t += h0[j] * W1[f * 7 + j];
        s[f] = t * d;
    }
#pragma unroll
    for (int q = 0; q < 4; q++)
        u1[i * 4 + q] = make_float4(s[q*4], s[q*4+1], s[q*4+2], s[q*4+3]);
}

// Layer 1: 16-thread group per dst node, register acc over CSR neighbor list.
// Fused epilogue: h1 = tanh(dinv*(acc+self)+b1); u2 = (h1 @ W2^T) * dinv.
__global__ void k_agg1(const unsigned int* __restrict__ sorted,
                       const int* __restrict__ row_ptr,
                       const float* __restrict__ u1, const float* __restrict__ dinv,
                       const float* __restrict__ b1, const float* __restrict__ W2,
                       float* __restrict__ u2, int n) {
    __shared__ float hbuf[16 * 16];
    int nl = threadIdx.x >> 4;           // 0..15: node within block
    int f = threadIdx.x & 15;
    int node = blockIdx.x * 16 + nl;
    if (node < n) {
        int s = row_ptr[node], e = row_ptr[node + 1];
        float acc = 0.0f;
        for (int j = s; j < e; j++) {
            int r = (int)(sorted[j] & 0x1FFFF);
            acc += u1[r * 16 + f];       // 64B coalesced per group; index broadcast
        }
        float d = dinv[node];
        hbuf[nl * 16 + f] = tanhf(d * (acc + u1[node * 16 + f]) + b1[f]);
    }
    __syncthreads();
    if (threadIdx.x < 128) {
        int nl2 = threadIdx.x >> 3;
        int g = threadIdx.x & 7;
        int node2 = blockIdx.x * 16 + nl2;
        if (node2 < n) {
            float t = 0.0f;
#pragma unroll
            for (int j = 0; j < 16; j++) t += hbuf[nl2 * 16 + j] * W2[g * 16 + j];
            u2[node2 * 8 + g] = t * dinv[node2];
        }
    }
}

// Layer 2: 8-thread group per dst node; h2 = tanh(dinv*(acc+self)+b2).
__global__ void k_agg2(const unsigned int* __restrict__ sorted,
                       const int* __restrict__ row_ptr,
                       const float* __restrict__ u2, const float* __restrict__ dinv,
                       const float* __restrict__ b2, float* __restrict__ h2, int n) {
    int node = blockIdx.x * 32 + (threadIdx.x >> 3);
    int f = threadIdx.x & 7;
    if (node >= n) return;
    int s = row_ptr[node], e = row_ptr[node + 1];
    float acc = 0.0f;
    for (int j = s; j < e; j++) {
        int r = (int)(sorted[j] & 0x1FFFF);
        acc += u2[r * 8 + f];            // 32B coalesced per group
    }
    float d = dinv[node];
    h2[node * 8 + f] = tanhf(d * (acc + u2[node * 8 + f]) + b2[f]);
}

// One wave per graph. batch is SORTED -> binary search node range, mean, dot W3.
__global__ void k_pool_out(const float4* __restrict__ h2q, const int* __restrict__ batch,
                           const float* __restrict__ W3, const float* __restrict__ b3,
                           float* __restrict__ out, int n) {
    int g = blockIdx.x;
    int lane = threadIdx.x;           // 64 threads = 1 wave
    int lo = 0, hi = n;
    while (lo < hi) { int m = (lo + hi) >> 1; if (batch[m] < g) lo = m + 1; else hi = m; }
    int start = lo;
    hi = n;
    while (lo < hi) { int m = (lo + hi) >> 1; if (batch[m] < g + 1) lo = m + 1; else hi = m; }
    int end = lo;

    float s[8];
#pragma unroll
    for (int f = 0; f < 8; f++) s[f] = 0.0f;
    for (int i = start + lane; i < end; i += 64) {
        float4 a0 = h2q[i * 2];
        float4 a1 = h2q[i * 2 + 1];
        s[0] += a0.x; s[1] += a0.y; s[2] += a0.z; s[3] += a0.w;
        s[4] += a1.x; s[5] += a1.y; s[6] += a1.z; s[7] += a1.w;
    }
#pragma unroll
    for (int off = 32; off >= 1; off >>= 1) {
#pragma unroll
        for (int f = 0; f < 8; f++) s[f] += __shfl_down(s[f], off, 64);
    }
    if (lane == 0) {
        float c = fmaxf((float)(end - start), 1.0f);
        float t = 0.0f;
#pragma unroll
        for (int f = 0; f < 8; f++) t += (s[f] / c) * W3[f];
        out[g] = t + b3[0];
    }
}

extern "C" void kernel_launch(void* const* d_in, const int* in_sizes, int n_in,
                              void* d_out, int out_size, void* d_ws, size_t ws_size,
                              hipStream_t stream) {
    const float* x    = (const float*)d_in[0];
    const int*   ei   = (const int*)d_in[1];
    const int*   batch= (const int*)d_in[2];
    const float* Wemb = (const float*)d_in[3];
    const float* bemb = (const float*)d_in[4];
    const float* W1   = (const float*)d_in[5];
    const float* b1   = (const float*)d_in[6];
    const float* W2   = (const float*)d_in[7];
    const float* b2   = (const float*)d_in[8];
    const float* W3   = (const float*)d_in[9];
    const float* b3   = (const float*)d_in[10];
    float* out = (float*)d_out;

    const int n = in_sizes[2];        // 100000
    const int E = in_sizes[1] / 2;    // 3200000
    const int G = out_size;           // 1024
    const int* row = ei;
    const int* col = ei + E;
    const int B = (n + NPB - 1) / NPB;   // 782

    // workspace (4B words): dinv[n] | u1[16n] (h2 aliases first 8n) | u2[8n] |
    //   bucketCnt[MAXB] | starts[MAXB+1] | bucketPos[MAXB] | row_ptr[n+1] | data[E]
    // total ~= 26n + 2.4K + E words ~= 23.3 MB
    float* ws   = (float*)d_ws;
    float* dinv = ws;                  // n
    float* u1   = ws + n;              // 16n
    float* u2   = ws + 17 * n;         // 8n
    float* h2   = u1;                  // aliases u1 (dead after k_agg1)
    int* bucketCnt = (int*)(ws + 25 * n);
    int* starts    = bucketCnt + MAXB;
    int* bucketPos = starts + MAXB + 1;
    int* row_ptr   = bucketPos + MAXB;           // n+1
    unsigned int* data = (unsigned int*)(row_ptr + n + 1);  // E entries

    int gridN = (n + BLK - 1) / BLK;

    k_init<<<1, 1024, 0, stream>>>(bucketCnt, row_ptr, n, E);
    k_count<<<256, BLK, 0, stream>>>(col, bucketCnt, E, B);
    k_scan<<<1, 1024, 0, stream>>>(bucketCnt, starts, bucketPos, B);
    k_place<<<256, BLK, 0, stream>>>(row, col, bucketPos, data, E, B);
    k_sort<<<B, BLK, 0, stream>>>(data, starts, row_ptr, dinv, n);
    k_node1<<<gridN, BLK, 0, stream>>>((const float4*)x, dinv, Wemb, bemb, W1,
                                       (float4*)u1, n);
    k_agg1<<<(n + 15) / 16, BLK, 0, stream>>>(data, row_ptr, u1, dinv, b1, W2, u2, n);
    k_agg2<<<(n + 31) / 32, BLK, 0, stream>>>(data, row_ptr, u2, dinv, b2, h2, n);
    k_pool_out<<<G, 64, 0, stream>>>((const float4*)h2, batch, W3, b3, out, n);
}

// Round 5
// 259.228 us; speedup vs baseline: 2.8363x; 1.3084x over previous
//
#include <hip/hip_runtime.h>
#include <hip/hip_fp16.h>

// GCN: N=100000 nodes (4 feats), E=3.2M edges, G=1024 graphs.
// out = mean-pool(tanh(gcn2(tanh(gcn1(embed(x)))))) @ W3.T + b3
//
// gcn_conv rewritten: u[i] = (h[i] @ W^T) * dinv[i];
// out[c] = dinv[c] * (sum_{edges r->c} u[r] + u[c]) + b   (self-loop folded in)
//
// R5: R4's k_agg1 was L2-miss bound (u1 f32 = 6.4MB > 4MB per-XCD L2; 105MB
// HBM-side fetch). Messages now fp16 (f32 accumulate): u1h = 3.2MB fits the
// per-XCD L2, gathers are 32B not 64B. 8-thread groups/node + 4x unrolled
// neighbor loop for MLP. Sorted edge list stores plain src index.

constexpr int BLK = 256;
constexpr int NPB = 128;            // dst nodes per bucket
constexpr int MAXB = 784;           // >= ceil(100000/128)=782
constexpr int CAP = 6144;           // LDS stage cap; bucket ~Poisson(4092), +32 sigma

__global__ void k_init(int* __restrict__ bucketCnt, int* __restrict__ row_ptr,
                       int n, int E) {
    int t = threadIdx.x;
    if (t < MAXB) bucketCnt[t] = 0;
    if (t == 0) row_ptr[n] = E;
}

__global__ void k_count(const int* __restrict__ col, int* __restrict__ bucketCnt,
                        int E, int B) {
    __shared__ int lcnt[MAXB];
    int chunk = (E + gridDim.x - 1) / gridDim.x;
    int begin = blockIdx.x * chunk;
    int end = min(E, begin + chunk);
    for (int t = threadIdx.x; t < MAXB; t += BLK) lcnt[t] = 0;
    __syncthreads();
    for (int e = begin + threadIdx.x; e < end; e += BLK)
        atomicAdd(&lcnt[col[e] >> 7], 1);
    __syncthreads();
    for (int t = threadIdx.x; t < B; t += BLK) {
        int c = lcnt[t];
        if (c) atomicAdd(&bucketCnt[t], c);
    }
}

__global__ void k_scan(const int* __restrict__ bucketCnt, int* __restrict__ starts,
                       int* __restrict__ bucketPos, int B) {
    __shared__ int a[1024], bb[1024];
    int t = threadIdx.x;
    int v = (t < B) ? bucketCnt[t] : 0;
    a[t] = v;
    __syncthreads();
    int* src = a; int* dst = bb;
#pragma unroll
    for (int off = 1; off < 1024; off <<= 1) {
        dst[t] = src[t] + (t >= off ? src[t - off] : 0);
        __syncthreads();
        int* tmp = src; src = dst; dst = tmp;
    }
    if (t == 0) starts[0] = 0;
    if (t < B) {
        starts[t + 1] = src[t];           // inclusive
        bucketPos[t] = src[t] - v;        // exclusive
    }
}

// Place edges into buckets: entry = (dst_local<<17) | src  (src<2^17, dloc<128)
__global__ void k_place(const int* __restrict__ row, const int* __restrict__ col,
                        int* __restrict__ bucketPos, unsigned int* __restrict__ data,
                        int E, int B) {
    __shared__ int lcnt[MAXB];
    __shared__ int lbase[MAXB];
    int chunk = (E + gridDim.x - 1) / gridDim.x;
    int begin = blockIdx.x * chunk;
    int end = min(E, begin + chunk);
    for (int t = threadIdx.x; t < MAXB; t += BLK) lcnt[t] = 0;
    __syncthreads();
    for (int e = begin + threadIdx.x; e < end; e += BLK)
        atomicAdd(&lcnt[col[e] >> 7], 1);
    __syncthreads();
    for (int t = threadIdx.x; t < B; t += BLK) {
        int c = lcnt[t];
        lbase[t] = c ? atomicAdd(&bucketPos[t], c) : 0;
        lcnt[t] = 0;
    }
    __syncthreads();
    for (int e = begin + threadIdx.x; e < end; e += BLK) {
        int c = col[e];
        int b = c >> 7;
        int off = atomicAdd(&lcnt[b], 1);
        data[lbase[b] + off] = ((unsigned int)(c & 127) << 17) | (unsigned int)row[e];
    }
}

// Per-bucket LDS counting sort (in place) + row_ptr + dinv. Final entries: src only.
__global__ void k_sort(unsigned int* __restrict__ data, const int* __restrict__ starts,
                       int* __restrict__ row_ptr, float* __restrict__ dinv, int n) {
    __shared__ unsigned int stage[CAP];
    __shared__ int hist[NPB];
    __shared__ int scanbuf[NPB];
    __shared__ int pos[NPB];
    int b = blockIdx.x;
    int t = threadIdx.x;
    int s = starts[b];
    int cnt = starts[b + 1] - s;
    for (int i = t; i < NPB; i += BLK) hist[i] = 0;
    __syncthreads();
    for (int i = t; i < cnt; i += BLK) {
        unsigned int p = data[s + i];
        if (i < CAP) stage[i] = p;
        atomicAdd(&hist[p >> 17], 1);
    }
    __syncthreads();
    int v = (t < NPB) ? hist[t] : 0;
    if (t < NPB) scanbuf[t] = v;
    __syncthreads();
#pragma unroll
    for (int off = 1; off < NPB; off <<= 1) {
        int add = 0;
        if (t < NPB && t >= off) add = scanbuf[t - off];
        __syncthreads();
        if (t < NPB) scanbuf[t] += add;
        __syncthreads();
    }
    if (t < NPB) {
        int excl = scanbuf[t] - v;
        pos[t] = excl;
        int node = b * NPB + t;
        if (node < n) {
            row_ptr[node] = s + excl;
            dinv[node] = rsqrtf((float)v + 1.0f);   // +1 self-loop
        }
    }
    __syncthreads();
    for (int i = t; i < cnt; i += BLK) {
        unsigned int p = (i < CAP) ? stage[i] : data[s + i];
        int off = atomicAdd(&pos[p >> 17], 1);
        data[s + off] = p & 0x1FFFF;               // strip dloc -> plain src
    }
}

// h0 = [x0*Wemb + bemb (4), x1, x2, x3]; u1h = fp16((h0 @ W1^T) * dinv)
__global__ void k_node1(const float4* __restrict__ x, const float* __restrict__ dinv,
                        const float* __restrict__ Wemb, const float* __restrict__ bemb,
                        const float* __restrict__ W1, __half* __restrict__ u1h, int n) {
    int i = blockIdx.x * BLK + threadIdx.x;
    if (i >= n) return;
    float4 xi = x[i];
    float h0[7];
#pragma unroll
    for (int j = 0; j < 4; j++) h0[j] = xi.x * Wemb[j] + bemb[j];
    h0[4] = xi.y; h0[5] = xi.z; h0[6] = xi.w;
    float d = dinv[i];
    float s[16];
#pragma unroll
    for (int f = 0; f < 16; f++) {
        float t = 0.0f;
#pragma unroll
        for (int j = 0; j < 7; j++) t += h0[j] * W1[f * 7 + j];
        s[f] = t * d;
    }
    union { __half2 h2[8]; uint4 u4[2]; } pk;
#pragma unroll
    for (int q = 0; q < 8; q++) pk.h2[q] = __floats2half2_rn(s[2*q], s[2*q+1]);
    uint4* dst = (uint4*)(u1h + (size_t)i * 16);
    dst[0] = pk.u4[0];
    dst[1] = pk.u4[1];
}

// Layer 1: 8-thread group per dst node; lane f holds features {2f,2f+1}.
// Gather fp16 half2, accumulate f32, 4x unroll. Fused epilogue:
// h1 = tanh(dinv*(acc+self)+b1); u2h = fp16((h1 @ W2^T) * dinv).
__global__ void k_agg1(const unsigned int* __restrict__ sorted,
                       const int* __restrict__ row_ptr,
                       const __half2* __restrict__ u1h2, const float* __restrict__ dinv,
                       const float* __restrict__ b1, const float* __restrict__ W2,
                       __half* __restrict__ u2h, int n) {
    __shared__ float hbuf[32][17];
    int nl = threadIdx.x >> 3;           // 0..31: node within block
    int f = threadIdx.x & 7;             // feature pair
    int node = blockIdx.x * 32 + nl;
    if (node < n) {
        int s = row_ptr[node], e = row_ptr[node + 1];
        float2 acc = make_float2(0.0f, 0.0f);
        int j = s;
        for (; j + 4 <= e; j += 4) {
            int r0 = sorted[j], r1 = sorted[j+1], r2 = sorted[j+2], r3 = sorted[j+3];
            float2 a0 = __half22float2(u1h2[r0 * 8 + f]);
            float2 a1 = __half22float2(u1h2[r1 * 8 + f]);
            float2 a2 = __half22float2(u1h2[r2 * 8 + f]);
            float2 a3 = __half22float2(u1h2[r3 * 8 + f]);
            acc.x += (a0.x + a1.x) + (a2.x + a3.x);
            acc.y += (a0.y + a1.y) + (a2.y + a3.y);
        }
        for (; j < e; j++) {
            float2 a = __half22float2(u1h2[sorted[j] * 8 + f]);
            acc.x += a.x; acc.y += a.y;
        }
        float2 self = __half22float2(u1h2[node * 8 + f]);
        float d = dinv[node];
        hbuf[nl][2*f]   = tanhf(d * (acc.x + self.x) + b1[2*f]);
        hbuf[nl][2*f+1] = tanhf(d * (acc.y + self.y) + b1[2*f+1]);
    }
    __syncthreads();
    int nl2 = threadIdx.x >> 3;
    int g = threadIdx.x & 7;
    int node2 = blockIdx.x * 32 + nl2;
    if (node2 < n) {
        float t = 0.0f;
#pragma unroll
        for (int j = 0; j < 16; j++) t += hbuf[nl2][j] * W2[g * 16 + j];
        u2h[node2 * 8 + g] = __float2half(t * dinv[node2]);
    }
}

// Layer 2: 4-thread group per dst node; lane f holds features {2f,2f+1}.
// h2 (f32) = tanh(dinv*(acc+self)+b2).
__global__ void k_agg2(const unsigned int* __restrict__ sorted,
                       const int* __restrict__ row_ptr,
                       const __half2* __restrict__ u2h2, const float* __restrict__ dinv,
                       const float* __restrict__ b2, float2* __restrict__ h2v, int n) {
    int node = blockIdx.x * 64 + (threadIdx.x >> 2);
    int f = threadIdx.x & 3;
    if (node >= n) return;
    int s = row_ptr[node], e = row_ptr[node + 1];
    float2 acc = make_float2(0.0f, 0.0f);
    int j = s;
    for (; j + 4 <= e; j += 4) {
        int r0 = sorted[j], r1 = sorted[j+1], r2 = sorted[j+2], r3 = sorted[j+3];
        float2 a0 = __half22float2(u2h2[r0 * 4 + f]);
        float2 a1 = __half22float2(u2h2[r1 * 4 + f]);
        float2 a2 = __half22float2(u2h2[r2 * 4 + f]);
        float2 a3 = __half22float2(u2h2[r3 * 4 + f]);
        acc.x += (a0.x + a1.x) + (a2.x + a3.x);
        acc.y += (a0.y + a1.y) + (a2.y + a3.y);
    }
    for (; j < e; j++) {
        float2 a = __half22float2(u2h2[sorted[j] * 4 + f]);
        acc.x += a.x; acc.y += a.y;
    }
    float2 self = __half22float2(u2h2[node * 4 + f]);
    float d = dinv[node];
    h2v[node * 4 + f] = make_float2(tanhf(d * (acc.x + self.x) + b2[2*f]),
                                    tanhf(d * (acc.y + self.y) + b2[2*f+1]));
}

// One wave per graph. batch is SORTED -> binary search node range, mean, dot W3.
__global__ void k_pool_out(const float4* __restrict__ h2q, const int* __restrict__ batch,
                           const float* __restrict__ W3, const float* __restrict__ b3,
                           float* __restrict__ out, int n) {
    int g = blockIdx.x;
    int lane = threadIdx.x;           // 64 threads = 1 wave
    int lo = 0, hi = n;
    while (lo < hi) { int m = (lo + hi) >> 1; if (batch[m] < g) lo = m + 1; else hi = m; }
    int start = lo;
    hi = n;
    while (lo < hi) { int m = (lo + hi) >> 1; if (batch[m] < g + 1) lo = m + 1; else hi = m; }
    int end = lo;

    float s[8];
#pragma unroll
    for (int f = 0; f < 8; f++) s[f] = 0.0f;
    for (int i = start + lane; i < end; i += 64) {
        float4 a0 = h2q[i * 2];
        float4 a1 = h2q[i * 2 + 1];
        s[0] += a0.x; s[1] += a0.y; s[2] += a0.z; s[3] += a0.w;
        s[4] += a1.x; s[5] += a1.y; s[6] += a1.z; s[7] += a1.w;
    }
#pragma unroll
    for (int off = 32; off >= 1; off >>= 1) {
#pragma unroll
        for (int f = 0; f < 8; f++) s[f] += __shfl_down(s[f], off, 64);
    }
    if (lane == 0) {
        float c = fmaxf((float)(end - start), 1.0f);
        float t = 0.0f;
#pragma unroll
        for (int f = 0; f < 8; f++) t += (s[f] / c) * W3[f];
        out[g] = t + b3[0];
    }
}

extern "C" void kernel_launch(void* const* d_in, const int* in_sizes, int n_in,
                              void* d_out, int out_size, void* d_ws, size_t ws_size,
                              hipStream_t stream) {
    const float* x    = (const float*)d_in[0];
    const int*   ei   = (const int*)d_in[1];
    const int*   batch= (const int*)d_in[2];
    const float* Wemb = (const float*)d_in[3];
    const float* bemb = (const float*)d_in[4];
    const float* W1   = (const float*)d_in[5];
    const float* b1   = (const float*)d_in[6];
    const float* W2   = (const float*)d_in[7];
    const float* b2   = (const float*)d_in[8];
    const float* W3   = (const float*)d_in[9];
    const float* b3   = (const float*)d_in[10];
    float* out = (float*)d_out;

    const int n = in_sizes[2];        // 100000
    const int E = in_sizes[1] / 2;    // 3200000
    const int G = out_size;           // 1024
    const int* row = ei;
    const int* col = ei + E;
    const int B = (n + NPB - 1) / NPB;   // 782

    // workspace (4B words): dinv[n] | u1h[16n halves = 8n] | u2h[8n halves = 4n] |
    //   h2[8n] | bucketCnt[MAXB] | starts[MAXB+1] | bucketPos[MAXB] | row_ptr[n+1] | data[E]
    float* ws    = (float*)d_ws;
    float* dinv  = ws;                      // n
    __half* u1h  = (__half*)(ws + n);       // 8n words
    __half* u2h  = (__half*)(ws + 9 * n);   // 4n words
    float* h2    = ws + 13 * n;             // 8n words
    int* bucketCnt = (int*)(ws + 21 * n);
    int* starts    = bucketCnt + MAXB;
    int* bucketPos = starts + MAXB + 1;
    int* row_ptr   = bucketPos + MAXB;                      // n+1
    unsigned int* data = (unsigned int*)(row_ptr + n + 1);  // E entries

    int gridN = (n + BLK - 1) / BLK;

    k_init<<<1, 1024, 0, stream>>>(bucketCnt, row_ptr, n, E);
    k_count<<<256, BLK, 0, stream>>>(col, bucketCnt, E, B);
    k_scan<<<1, 1024, 0, stream>>>(bucketCnt, starts, bucketPos, B);
    k_place<<<256, BLK, 0, stream>>>(row, col, bucketPos, data, E, B);
    k_sort<<<B, BLK, 0, stream>>>(data, starts, row_ptr, dinv, n);
    k_node1<<<gridN, BLK, 0, stream>>>((const float4*)x, dinv, Wemb, bemb, W1, u1h, n);
    k_agg1<<<(n + 31) / 32, BLK, 0, stream>>>(data, row_ptr, (const __half2*)u1h,
                                              dinv, b1, W2, u2h, n);
    k_agg2<<<(n + 63) / 64, BLK, 0, stream>>>(data, row_ptr, (const __half2*)u2h,
                                              dinv, b2, (float2*)h2, n);
    k_pool_out<<<G, 64, 0, stream>>>((const float4*)h2, batch, W3, b3, out, n);
}

// Round 6
// 240.762 us; speedup vs baseline: 3.0538x; 1.0767x over previous
//
#include <hip/hip_runtime.h>
#include <hip/hip_fp16.h>

// GCN: N=100000 nodes (4 feats), E=3.2M edges, G=1024 graphs.
// out = mean-pool(tanh(gcn2(tanh(gcn1(embed(x)))))) @ W3.T + b3
//
// gcn_conv rewritten: u[i] = (h[i] @ W^T) * dinv[i];
// out[c] = dinv[c] * (sum_{edges r->c} u[r] + u[c]) + b   (self-loop folded in)
//
// R6: k_place was write-scatter bound (57-67MB HBM writes for 12.8MB of data:
// random 4B writes -> partial-line RMW). Now: fixed-capacity padded buckets
// (no count/scan passes at all) + per-block LDS staging so placement writes
// are contiguous per-bucket runs (~128B). Messages fp16 (f32 accumulate),
// CSR register-accumulate aggregation (R4/R5 structure).

constexpr int BLK  = 256;
constexpr int NPB  = 256;            // dst nodes per bucket (dloc = 8 bits)
constexpr int NBMX = 512;            // padded bucket-array size (NB=391)
constexpr int CAPB = 9216;           // slots per bucket; mean 8163, sigma 90 -> 11.7 sigma
constexpr int CAPS = 12544;          // per-block stage capacity (chunk <= CAPS)

__global__ void k_init(int* __restrict__ bucketCnt) {
    bucketCnt[threadIdx.x] = 0;      // 512 threads
}

// Single-pass placement: per block, LDS histogram over buckets, global space
// reservation (1 atomic per block-bucket), LDS-scan, LDS-stage scatter, then
// contiguous per-bucket run copy to global. entry = (dloc<<17) | src.
__global__ void k_place(const int* __restrict__ row, const int* __restrict__ col,
                        int* __restrict__ bucketCnt, unsigned int* __restrict__ data,
                        int E, int NB) {
    __shared__ unsigned int stage[CAPS];             // 50.2 KB
    __shared__ int hist[NBMX], lbase[NBMX], sstart[NBMX], pos[NBMX];
    __shared__ int scanb[BLK];
    int t = threadIdx.x;
    int chunk = (E + gridDim.x - 1) / gridDim.x;
    int begin = blockIdx.x * chunk;
    int end = min(E, begin + chunk);
    for (int i = t; i < NBMX; i += BLK) hist[i] = 0;
    __syncthreads();
    for (int e = begin + t; e < end; e += BLK)
        atomicAdd(&hist[col[e] >> 8], 1);
    __syncthreads();
    // thread t owns bins 2t, 2t+1 (NBMX = 2*BLK)
    int b0 = 2 * t, b1 = 2 * t + 1;
    int h0 = hist[b0], h1 = hist[b1];
    int tsum = h0 + h1;
    scanb[t] = tsum;
    __syncthreads();
#pragma unroll
    for (int off = 1; off < BLK; off <<= 1) {
        int add = (t >= off) ? scanb[t - off] : 0;
        __syncthreads();
        scanb[t] += add;
        __syncthreads();
    }
    int excl = scanb[t] - tsum;                      // stage offset of bin b0
    sstart[b0] = excl;       sstart[b1] = excl + h0;
    pos[b0]    = excl;       pos[b1]    = excl + h0;
    lbase[b0] = h0 ? atomicAdd(&bucketCnt[b0], h0) : 0;
    lbase[b1] = h1 ? atomicAdd(&bucketCnt[b1], h1) : 0;
    __syncthreads();
    for (int e = begin + t; e < end; e += BLK) {
        int c = col[e];
        int b = c >> 8;
        int o = atomicAdd(&pos[b], 1);
        stage[o] = ((unsigned int)(c & 255) << 17) | (unsigned int)row[e];
    }
    __syncthreads();
    // copy per-bucket runs contiguously (one wave per bucket, round-robin)
    int wave = t >> 6, lane = t & 63;
    for (int b = wave; b < NB; b += (BLK / 64)) {
        int c = hist[b];
        int s = sstart[b];
        unsigned int dst = (unsigned int)b * CAPB + (unsigned int)lbase[b];
        for (int k = lane; k < c; k += 64)
            data[dst + k] = stage[s + k];
    }
}

// Per-bucket LDS counting sort (in place) -> dst-sorted src lists + rs/re + dinv.
__global__ void k_sort(unsigned int* __restrict__ data, const int* __restrict__ bucketCnt,
                       int* __restrict__ rs, int* __restrict__ re,
                       float* __restrict__ dinv, int n) {
    __shared__ unsigned int stage[CAPB];             // 36.9 KB
    __shared__ int hist[NPB], scanbuf[NPB], pos[NPB];
    int b = blockIdx.x;
    int t = threadIdx.x;                             // BLK == NPB == 256
    int base = b * CAPB;
    int cnt = min(bucketCnt[b], CAPB);
    hist[t] = 0;
    __syncthreads();
    for (int i = t; i < cnt; i += BLK) {
        unsigned int p = data[base + i];
        stage[i] = p;
        atomicAdd(&hist[p >> 17], 1);
    }
    __syncthreads();
    int v = hist[t];
    scanbuf[t] = v;
    __syncthreads();
#pragma unroll
    for (int off = 1; off < NPB; off <<= 1) {
        int add = (t >= off) ? scanbuf[t - off] : 0;
        __syncthreads();
        scanbuf[t] += add;
        __syncthreads();
    }
    int excl = scanbuf[t] - v;
    pos[t] = excl;
    int node = b * NPB + t;
    if (node < n) {
        rs[node] = base + excl;
        re[node] = base + excl + v;
        dinv[node] = rsqrtf((float)v + 1.0f);        // +1 self-loop
    }
    __syncthreads();
    for (int i = t; i < cnt; i += BLK) {
        unsigned int p = stage[i];
        int off = atomicAdd(&pos[p >> 17], 1);
        data[base + off] = p & 0x1FFFF;              // plain src index
    }
}

// h0 = [x0*Wemb + bemb (4), x1, x2, x3]; u1h = fp16((h0 @ W1^T) * dinv)
__global__ void k_node1(const float4* __restrict__ x, const float* __restrict__ dinv,
                        const float* __restrict__ Wemb, const float* __restrict__ bemb,
                        const float* __restrict__ W1, __half* __restrict__ u1h, int n) {
    int i = blockIdx.x * BLK + threadIdx.x;
    if (i >= n) return;
    float4 xi = x[i];
    float h0[7];
#pragma unroll
    for (int j = 0; j < 4; j++) h0[j] = xi.x * Wemb[j] + bemb[j];
    h0[4] = xi.y; h0[5] = xi.z; h0[6] = xi.w;
    float d = dinv[i];
    float s[16];
#pragma unroll
    for (int f = 0; f < 16; f++) {
        float t = 0.0f;
#pragma unroll
        for (int j = 0; j < 7; j++) t += h0[j] * W1[f * 7 + j];
        s[f] = t * d;
    }
    union { __half2 h2[8]; uint4 u4[2]; } pk;
#pragma unroll
    for (int q = 0; q < 8; q++) pk.h2[q] = __floats2half2_rn(s[2*q], s[2*q+1]);
    uint4* dst = (uint4*)(u1h + (size_t)i * 16);
    dst[0] = pk.u4[0];
    dst[1] = pk.u4[1];
}

// Layer 1: 8-thread group per dst node; lane f holds features {2f,2f+1}.
// Gather fp16 half2, accumulate f32, 4x unroll. Fused epilogue:
// h1 = tanh(dinv*(acc+self)+b1); u2h = fp16((h1 @ W2^T) * dinv).
__global__ void k_agg1(const unsigned int* __restrict__ sorted,
                       const int* __restrict__ rs, const int* __restrict__ re,
                       const __half2* __restrict__ u1h2, const float* __restrict__ dinv,
                       const float* __restrict__ b1, const float* __restrict__ W2,
                       __half* __restrict__ u2h, int n) {
    __shared__ float hbuf[32][17];
    int nl = threadIdx.x >> 3;           // 0..31: node within block
    int f = threadIdx.x & 7;             // feature pair
    int node = blockIdx.x * 32 + nl;
    if (node < n) {
        int s = rs[node], e = re[node];
        float2 acc = make_float2(0.0f, 0.0f);
        int j = s;
        for (; j + 4 <= e; j += 4) {
            int r0 = sorted[j], r1 = sorted[j+1], r2 = sorted[j+2], r3 = sorted[j+3];
            float2 a0 = __half22float2(u1h2[r0 * 8 + f]);
            float2 a1 = __half22float2(u1h2[r1 * 8 + f]);
            float2 a2 = __half22float2(u1h2[r2 * 8 + f]);
            float2 a3 = __half22float2(u1h2[r3 * 8 + f]);
            acc.x += (a0.x + a1.x) + (a2.x + a3.x);
            acc.y += (a0.y + a1.y) + (a2.y + a3.y);
        }
        for (; j < e; j++) {
            float2 a = __half22float2(u1h2[sorted[j] * 8 + f]);
            acc.x += a.x; acc.y += a.y;
        }
        float2 self = __half22float2(u1h2[node * 8 + f]);
        float d = dinv[node];
        hbuf[nl][2*f]   = tanhf(d * (acc.x + self.x) + b1[2*f]);
        hbuf[nl][2*f+1] = tanhf(d * (acc.y + self.y) + b1[2*f+1]);
    }
    __syncthreads();
    int nl2 = threadIdx.x >> 3;
    int g = threadIdx.x & 7;
    int node2 = blockIdx.x * 32 + nl2;
    if (node2 < n) {
        float t = 0.0f;
#pragma unroll
        for (int j = 0; j < 16; j++) t += hbuf[nl2][j] * W2[g * 16 + j];
        u2h[node2 * 8 + g] = __float2half(t * dinv[node2]);
    }
}

// Layer 2: 4-thread group per dst node; h2h = fp16(tanh(dinv*(acc+self)+b2)).
__global__ void k_agg2(const unsigned int* __restrict__ sorted,
                       const int* __restrict__ rs, const int* __restrict__ re,
                       const __half2* __restrict__ u2h2, const float* __restrict__ dinv,
                       const float* __restrict__ b2, __half2* __restrict__ h2h2, int n) {
    int node = blockIdx.x * 64 + (threadIdx.x >> 2);
    int f = threadIdx.x & 3;
    if (node >= n) return;
    int s = rs[node], e = re[node];
    float2 acc = make_float2(0.0f, 0.0f);
    int j = s;
    for (; j + 4 <= e; j += 4) {
        int r0 = sorted[j], r1 = sorted[j+1], r2 = sorted[j+2], r3 = sorted[j+3];
        float2 a0 = __half22float2(u2h2[r0 * 4 + f]);
        float2 a1 = __half22float2(u2h2[r1 * 4 + f]);
        float2 a2 = __half22float2(u2h2[r2 * 4 + f]);
        float2 a3 = __half22float2(u2h2[r3 * 4 + f]);
        acc.x += (a0.x + a1.x) + (a2.x + a3.x);
        acc.y += (a0.y + a1.y) + (a2.y + a3.y);
    }
    for (; j < e; j++) {
        float2 a = __half22float2(u2h2[sorted[j] * 4 + f]);
        acc.x += a.x; acc.y += a.y;
    }
    float2 self = __half22float2(u2h2[node * 4 + f]);
    float d = dinv[node];
    h2h2[node * 4 + f] = __floats2half2_rn(tanhf(d * (acc.x + self.x) + b2[2*f]),
                                           tanhf(d * (acc.y + self.y) + b2[2*f+1]));
}

// One wave per graph. batch is SORTED -> binary search node range, mean, dot W3.
__global__ void k_pool_out(const uint4* __restrict__ h2q, const int* __restrict__ batch,
                           const float* __restrict__ W3, const float* __restrict__ b3,
                           float* __restrict__ out, int n) {
    int g = blockIdx.x;
    int lane = threadIdx.x;           // 64 threads = 1 wave
    int lo = 0, hi = n;
    while (lo < hi) { int m = (lo + hi) >> 1; if (batch[m] < g) lo = m + 1; else hi = m; }
    int start = lo;
    hi = n;
    while (lo < hi) { int m = (lo + hi) >> 1; if (batch[m] < g + 1) lo = m + 1; else hi = m; }
    int end = lo;

    float s[8];
#pragma unroll
    for (int f = 0; f < 8; f++) s[f] = 0.0f;
    for (int i = start + lane; i < end; i += 64) {
        uint4 q = h2q[i];                 // 8 halves
        const __half2* ph = (const __half2*)&q;
#pragma unroll
        for (int p = 0; p < 4; p++) {
            float2 a = __half22float2(ph[p]);
            s[2*p]   += a.x;
            s[2*p+1] += a.y;
        }
    }
#pragma unroll
    for (int off = 32; off >= 1; off >>= 1) {
#pragma unroll
        for (int f = 0; f < 8; f++) s[f] += __shfl_down(s[f], off, 64);
    }
    if (lane == 0) {
        float c = fmaxf((float)(end - start), 1.0f);
        float t = 0.0f;
#pragma unroll
        for (int f = 0; f < 8; f++) t += (s[f] / c) * W3[f];
        out[g] = t + b3[0];
    }
}

extern "C" void kernel_launch(void* const* d_in, const int* in_sizes, int n_in,
                              void* d_out, int out_size, void* d_ws, size_t ws_size,
                              hipStream_t stream) {
    const float* x    = (const float*)d_in[0];
    const int*   ei   = (const int*)d_in[1];
    const int*   batch= (const int*)d_in[2];
    const float* Wemb = (const float*)d_in[3];
    const float* bemb = (const float*)d_in[4];
    const float* W1   = (const float*)d_in[5];
    const float* b1   = (const float*)d_in[6];
    const float* W2   = (const float*)d_in[7];
    const float* b2   = (const float*)d_in[8];
    const float* W3   = (const float*)d_in[9];
    const float* b3   = (const float*)d_in[10];
    float* out = (float*)d_out;

    const int n = in_sizes[2];        // 100000
    const int E = in_sizes[1] / 2;    // 3200000
    const int G = out_size;           // 1024
    const int* row = ei;
    const int* col = ei + E;
    const int NB = (n + NPB - 1) / NPB;   // 391

    // workspace (4B words): dinv[n] | u1h(8n) | u2h(4n) | h2h(4n) | rs[n] | re[n] |
    //   bucketCnt[512] | data[NBMX? no: 392*CAPB]  -> total ~5.51M words = 22.0 MB
    float* ws    = (float*)d_ws;
    float* dinv  = ws;                       // n
    __half* u1h  = (__half*)(ws + n);        // 8n words
    __half* u2h  = (__half*)(ws + 9 * n);    // 4n words
    __half* h2h  = (__half*)(ws + 13 * n);   // 4n words
    int* rs      = (int*)(ws + 17 * n);      // n
    int* re      = rs + n;                   // n
    int* bucketCnt = re + n;                 // 512
    unsigned int* data = (unsigned int*)(bucketCnt + 512);  // 392*CAPB words

    int gridN = (n + BLK - 1) / BLK;
    int gridP = (E + CAPS - 1) / CAPS;       // 256; guarantees chunk <= CAPS

    k_init<<<1, 512, 0, stream>>>(bucketCnt);
    k_place<<<gridP, BLK, 0, stream>>>(row, col, bucketCnt, data, E, NB);
    k_sort<<<NB, BLK, 0, stream>>>(data, bucketCnt, rs, re, dinv, n);
    k_node1<<<gridN, BLK, 0, stream>>>((const float4*)x, dinv, Wemb, bemb, W1, u1h, n);
    k_agg1<<<(n + 31) / 32, BLK, 0, stream>>>(data, rs, re, (const __half2*)u1h,
                                              dinv, b1, W2, u2h, n);
    k_agg2<<<(n + 63) / 64, BLK, 0, stream>>>(data, rs, re, (const __half2*)u2h,
                                              dinv, b2, (__half2*)h2h, n);
    k_pool_out<<<G, 64, 0, stream>>>((const uint4*)h2h, batch, W3, b3, out, n);
}